// Round 1
// baseline (929.757 us; speedup 1.0000x reference)
//
#include <hip/hip_runtime.h>
#include <hip/hip_bf16.h>

#define Nn 50000
#define Ee 800000
#define INF_ 128
#define HIDF 96
#define HH 8
#define DD 12
#define GG 64
#define OUTF 10

// ---------------- degree histogram ----------------
__global__ void hist_kernel(const int* __restrict__ src, const int* __restrict__ dst,
                            int* cnt_out, int* cnt_in, int E) {
    int e = blockIdx.x * 256 + threadIdx.x;
    if (e < E) {
        atomicAdd(&cnt_out[src[e]], 1);
        atomicAdd(&cnt_in[dst[e]], 1);
    }
}

// ---------------- exclusive scan of cnt_in -> row_start (single block) ----------------
__global__ __launch_bounds__(1024) void scan_kernel(const int* __restrict__ cnt_in,
                                                    int* __restrict__ row_start, int N) {
    __shared__ int part[1024];
    int t = threadIdx.x;
    int chunk = (N + 1023) / 1024;
    int beg = t * chunk;
    int end = min(beg + chunk, N);
    int s = 0;
    for (int i = beg; i < end; ++i) s += cnt_in[i];
    part[t] = s;
    __syncthreads();
    for (int off = 1; off < 1024; off *= 2) {
        int v = (t >= off) ? part[t - off] : 0;
        __syncthreads();
        part[t] += v;
        __syncthreads();
    }
    int pre = (t == 0) ? 0 : part[t - 1];
    for (int i = beg; i < end; ++i) { row_start[i] = pre; pre += cnt_in[i]; }
    if (t == 1023) row_start[N] = part[1023];
}

// ---------------- per-node setup: cursor copy + inv-sqrt degrees ----------------
__global__ void node_setup(const int* __restrict__ cnt_in, const int* __restrict__ cnt_out,
                           const int* __restrict__ row_start, int* __restrict__ cursor,
                           float* __restrict__ degI_is, float* __restrict__ degO_is, int N) {
    int n = blockIdx.x * 256 + threadIdx.x;
    if (n < N) {
        cursor[n] = row_start[n];
        degI_is[n] = rsqrtf((float)max(cnt_in[n], 1));
        degO_is[n] = rsqrtf((float)max(cnt_out[n], 1));
    }
}

// ---------------- CSR fill: csr_src[slot] = src[e] for edges grouped by dst ----------------
__global__ void fill_kernel(const int* __restrict__ src, const int* __restrict__ dst,
                            int* __restrict__ cursor, int* __restrict__ csr_src, int E) {
    int e = blockIdx.x * 256 + threadIdx.x;
    if (e < E) {
        int slot = atomicAdd(&cursor[dst[e]], 1);
        csr_src[slot] = src[e];
    }
}

// ---------------- staged-LDS GEMM: out[N x 96] = (rowScale? diag(rowScale):I) * A[N x K] @ W[K x 96] (+bias) ----------------
// block: 192 threads, tile 64 rows x 96 cols, thread tile 8x4, K staged by 32.
__global__ __launch_bounds__(192) void gemm96(const float* __restrict__ A, int K,
                                              const float* __restrict__ W,
                                              const float* __restrict__ bias,
                                              const float* __restrict__ rowScale,
                                              float* __restrict__ out, int N) {
    __shared__ float A_lds[64 * 36];   // stride 36 floats (pad 4) - 16B aligned rows
    __shared__ float W_lds[32 * 96];
    const int t = threadIdx.x;
    const int row0 = blockIdx.x * 64;
    const int tcol = t % 24;
    const int trow = t / 24;  // 0..7
    float acc[8][4];
#pragma unroll
    for (int i = 0; i < 8; ++i)
#pragma unroll
        for (int j = 0; j < 4; ++j) acc[i][j] = 0.f;

    for (int k0 = 0; k0 < K; k0 += 32) {
        // load W chunk: rows k0..k0+31, each 96 floats = 24 float4
        for (int i = t; i < 32 * 24; i += 192) {
            ((float4*)W_lds)[i] = ((const float4*)W)[(size_t)k0 * 24 + i];
        }
        // load A chunk: 64 rows x 32 cols (8 float4 per row)
        for (int i = t; i < 64 * 8; i += 192) {
            int r = i / 8, kk = i % 8;
            int gr = row0 + r;
            float4 v = make_float4(0.f, 0.f, 0.f, 0.f);
            if (gr < N) {
                v = *((const float4*)(A + (size_t)gr * K + k0 + kk * 4));
                if (rowScale) {
                    float s = rowScale[gr];
                    v.x *= s; v.y *= s; v.z *= s; v.w *= s;
                }
            }
            *((float4*)(A_lds + r * 36 + kk * 4)) = v;
        }
        __syncthreads();
#pragma unroll
        for (int kk4 = 0; kk4 < 8; ++kk4) {
            float4 a[8];
#pragma unroll
            for (int i = 0; i < 8; ++i)
                a[i] = *((const float4*)(A_lds + (trow + 8 * i) * 36 + kk4 * 4));
#pragma unroll
            for (int kk = 0; kk < 4; ++kk) {
                float wv[4];
#pragma unroll
                for (int j = 0; j < 4; ++j)
                    wv[j] = W_lds[(kk4 * 4 + kk) * 96 + tcol + 24 * j];
#pragma unroll
                for (int i = 0; i < 8; ++i) {
                    float av = (kk == 0) ? a[i].x : (kk == 1) ? a[i].y : (kk == 2) ? a[i].z : a[i].w;
#pragma unroll
                    for (int j = 0; j < 4; ++j) acc[i][j] = fmaf(av, wv[j], acc[i][j]);
                }
            }
        }
        __syncthreads();
    }
    // epilogue
#pragma unroll
    for (int j = 0; j < 4; ++j) {
        int c = tcol + 24 * j;
        float b = bias ? bias[c] : 0.f;
#pragma unroll
        for (int i = 0; i < 8; ++i) {
            int gr = row0 + trow + 8 * i;
            if (gr < N) out[(size_t)gr * 96 + c] = acc[i][j] + b;
        }
    }
}

// ---------------- GraphConv aggregate: hout[n][f] = relu(degI*sum_{in-edges}(hW[src][f]) + b[f]) ----------------
__global__ __launch_bounds__(192) void gc_agg(const float* __restrict__ hW,
                                              const int* __restrict__ row_start,
                                              const int* __restrict__ csr_src,
                                              const float* __restrict__ degI_is,
                                              const float* __restrict__ bias,
                                              float* __restrict__ hout, int N) {
    int n = blockIdx.x * 2 + threadIdx.x / 96;
    int f = threadIdx.x % 96;
    if (n >= N) return;
    int beg = row_start[n], end = row_start[n + 1];
    float s = 0.f;
    for (int e = beg; e < end; ++e) {
        int sn = csr_src[e];
        s += hW[(size_t)sn * 96 + f];
    }
    float v = s * degI_is[n] + bias[f];
    hout[(size_t)n * 96 + f] = fmaxf(v, 0.f);
}

// ---------------- GATv2 fused attention+aggregate, online softmax, thread = (node, head) ----------------
__global__ __launch_bounds__(256) void gat_agg(const float* __restrict__ fs,
                                               const float* __restrict__ fd,
                                               const float* __restrict__ attn,
                                               const int* __restrict__ row_start,
                                               const int* __restrict__ csr_src,
                                               float* __restrict__ hout, int N) {
    int tid = blockIdx.x * 256 + threadIdx.x;
    int n = tid >> 3, hd = tid & 7;
    if (n >= N) return;
    float att[12], fdv[12];
    {
        const float4* ap = (const float4*)(attn + hd * 12);
        float4 a0 = ap[0], a1 = ap[1], a2 = ap[2];
        att[0]=a0.x; att[1]=a0.y; att[2]=a0.z; att[3]=a0.w;
        att[4]=a1.x; att[5]=a1.y; att[6]=a1.z; att[7]=a1.w;
        att[8]=a2.x; att[9]=a2.y; att[10]=a2.z; att[11]=a2.w;
        const float4* dp = (const float4*)(fd + (size_t)n * 96 + hd * 12);
        float4 d0 = dp[0], d1 = dp[1], d2 = dp[2];
        fdv[0]=d0.x; fdv[1]=d0.y; fdv[2]=d0.z; fdv[3]=d0.w;
        fdv[4]=d1.x; fdv[5]=d1.y; fdv[6]=d1.z; fdv[7]=d1.w;
        fdv[8]=d2.x; fdv[9]=d2.y; fdv[10]=d2.z; fdv[11]=d2.w;
    }
    int beg = row_start[n], end = row_start[n + 1];
    float m = -3.0e38f, den = 0.f;
    float acc[12];
#pragma unroll
    for (int d = 0; d < 12; ++d) acc[d] = 0.f;
    for (int e = beg; e < end; ++e) {
        int s = csr_src[e];
        const float4* sp = (const float4*)(fs + (size_t)s * 96 + hd * 12);
        float4 s0 = sp[0], s1 = sp[1], s2 = sp[2];
        float fsv[12];
        fsv[0]=s0.x; fsv[1]=s0.y; fsv[2]=s0.z; fsv[3]=s0.w;
        fsv[4]=s1.x; fsv[5]=s1.y; fsv[6]=s1.z; fsv[7]=s1.w;
        fsv[8]=s2.x; fsv[9]=s2.y; fsv[10]=s2.z; fsv[11]=s2.w;
        float logit = 0.f;
#pragma unroll
        for (int d = 0; d < 12; ++d) {
            float u = fsv[d] + fdv[d];
            u = u > 0.f ? u : 0.2f * u;
            logit = fmaf(u, att[d], logit);
        }
        if (logit > m) {
            float c = __expf(m - logit);
            den *= c;
#pragma unroll
            for (int d = 0; d < 12; ++d) acc[d] *= c;
            m = logit;
        }
        float w = __expf(logit - m);
        den += w;
#pragma unroll
        for (int d = 0; d < 12; ++d) acc[d] = fmaf(w, fsv[d], acc[d]);
    }
    float inv = den > 0.f ? 1.f / den : 0.f;
    float* op = hout + (size_t)n * 96 + hd * 12;
#pragma unroll
    for (int d = 0; d < 12; ++d) op[d] = fmaxf(acc[d] * inv, 0.f);
}

// ---------------- per-graph max readout (values >= 0, hg zero-inited) ----------------
__global__ void readout_max(const float* __restrict__ h, const int* __restrict__ graph_id,
                            float* __restrict__ hg, int N) {
    int tid = blockIdx.x * 256 + threadIdx.x;
    if (tid >= N * 96) return;
    int n = tid / 96, f = tid % 96;
    int g = graph_id[n];
    float v = h[tid];
    atomicMax((int*)&hg[(size_t)g * 96 + f], __float_as_int(v));
}

// ---------------- classifier MLP: one block per graph ----------------
__global__ __launch_bounds__(96) void mlp_kernel(const float* __restrict__ hg,
                                                 const float* __restrict__ Wc1, const float* __restrict__ bc1,
                                                 const float* __restrict__ Wc2, const float* __restrict__ bc2,
                                                 const float* __restrict__ Wc3, const float* __restrict__ bc3,
                                                 float* __restrict__ out) {
    int g = blockIdx.x;
    int t = threadIdx.x;
    __shared__ float z0[96], z1[96], z2[48];
    z0[t] = hg[(size_t)g * 96 + t];
    __syncthreads();
    float s = bc1[t];
    for (int k = 0; k < 96; ++k) s = fmaf(z0[k], Wc1[k * 96 + t], s);
    z1[t] = fmaxf(s, 0.f);
    __syncthreads();
    if (t < 48) {
        float s2 = bc2[t];
        for (int k = 0; k < 96; ++k) s2 = fmaf(z1[k], Wc2[k * 48 + t], s2);
        z2[t] = fmaxf(s2, 0.f);
    }
    __syncthreads();
    if (t < 10) {
        float s3 = bc3[t];
        for (int k = 0; k < 48; ++k) s3 = fmaf(z2[k], Wc3[k * 10 + t], s3);
        out[(size_t)g * 10 + t] = s3;
    }
}

extern "C" void kernel_launch(void* const* d_in, const int* in_sizes, int n_in,
                              void* d_out, int out_size, void* d_ws, size_t ws_size,
                              hipStream_t stream) {
    const float* x        = (const float*)d_in[0];
    const int*   src      = (const int*)d_in[1];
    const int*   dst      = (const int*)d_in[2];
    const int*   graph_id = (const int*)d_in[3];
    const float* W1  = (const float*)d_in[4];
    const float* b1  = (const float*)d_in[5];
    const float* W2  = (const float*)d_in[6];
    const float* b2  = (const float*)d_in[7];
    const float* Ws  = (const float*)d_in[8];
    const float* bs  = (const float*)d_in[9];
    const float* Wd  = (const float*)d_in[10];
    const float* bd  = (const float*)d_in[11];
    const float* attn = (const float*)d_in[12];
    const float* Wc1 = (const float*)d_in[13];
    const float* bc1 = (const float*)d_in[14];
    const float* Wc2 = (const float*)d_in[15];
    const float* bc2 = (const float*)d_in[16];
    const float* Wc3 = (const float*)d_in[17];
    const float* bc3 = (const float*)d_in[18];
    float* out = (float*)d_out;

    // workspace layout (256B aligned)
    char* ws = (char*)d_ws;
    size_t off = 0;
    auto alloc = [&](size_t bytes) {
        char* p = ws + off;
        off = (off + bytes + 255) & ~(size_t)255;
        return p;
    };
    int*   cnt_in    = (int*)alloc(Nn * 4);
    int*   cnt_out   = (int*)alloc(Nn * 4);
    int*   row_start = (int*)alloc((Nn + 1) * 4);
    int*   cursor    = (int*)alloc(Nn * 4);
    int*   csr_src   = (int*)alloc(Ee * 4);
    float* degI_is   = (float*)alloc(Nn * 4);
    float* degO_is   = (float*)alloc(Nn * 4);
    float* bufH      = (float*)alloc((size_t)Nn * 96 * 4);
    float* bufT      = (float*)alloc((size_t)Nn * 96 * 4);
    float* bufFd     = (float*)alloc((size_t)Nn * 96 * 4);
    float* hg        = (float*)alloc(GG * 96 * 4);

    hipMemsetAsync(cnt_in, 0, Nn * 4, stream);
    hipMemsetAsync(cnt_out, 0, Nn * 4, stream);
    hipMemsetAsync(hg, 0, GG * 96 * 4, stream);

    int eb = (Ee + 255) / 256;
    hist_kernel<<<eb, 256, 0, stream>>>(src, dst, cnt_out, cnt_in, Ee);
    scan_kernel<<<1, 1024, 0, stream>>>(cnt_in, row_start, Nn);
    node_setup<<<(Nn + 255) / 256, 256, 0, stream>>>(cnt_in, cnt_out, row_start, cursor,
                                                     degI_is, degO_is, Nn);
    fill_kernel<<<eb, 256, 0, stream>>>(src, dst, cursor, csr_src, Ee);

    int gemm_blocks = (Nn + 63) / 64;
    int agg_blocks  = (Nn + 1) / 2;
    int gat_blocks  = (Nn * 8 + 255) / 256;

    // GraphConv 1: x[N,128] -> bufH
    gemm96<<<gemm_blocks, 192, 0, stream>>>(x, 128, W1, nullptr, degO_is, bufT, Nn);
    gc_agg<<<agg_blocks, 192, 0, stream>>>(bufT, row_start, csr_src, degI_is, b1, bufH, Nn);
    // GraphConv 2
    gemm96<<<gemm_blocks, 192, 0, stream>>>(bufH, 96, W2, nullptr, degO_is, bufT, Nn);
    gc_agg<<<agg_blocks, 192, 0, stream>>>(bufT, row_start, csr_src, degI_is, b2, bufH, Nn);

    // 3x GATv2
    for (int l = 0; l < 3; ++l) {
        const float* Wsl = Ws + (size_t)l * 96 * 96;
        const float* bsl = bs + (size_t)l * 96;
        const float* Wdl = Wd + (size_t)l * 96 * 96;
        const float* bdl = bd + (size_t)l * 96;
        const float* atl = attn + (size_t)l * 96;
        gemm96<<<gemm_blocks, 192, 0, stream>>>(bufH, 96, Wsl, bsl, nullptr, bufT, Nn);
        gemm96<<<gemm_blocks, 192, 0, stream>>>(bufH, 96, Wdl, bdl, nullptr, bufFd, Nn);
        gat_agg<<<gat_blocks, 256, 0, stream>>>(bufT, bufFd, atl, row_start, csr_src, bufH, Nn);
    }

    // readout + MLP
    readout_max<<<(Nn * 96 + 255) / 256, 256, 0, stream>>>(bufH, graph_id, hg, Nn);
    mlp_kernel<<<GG, 96, 0, stream>>>(hg, Wc1, bc1, Wc2, bc2, Wc3, bc3, out);
}

// Round 2
// 775.390 us; speedup vs baseline: 1.1991x; 1.1991x over previous
//
#include <hip/hip_runtime.h>
#include <hip/hip_bf16.h>

#define Nn 50000
#define Ee 800000
#define INF_ 128
#define HIDF 96
#define HH 8
#define DD 12
#define GG 64
#define OUTF 10

// ---------------- degree histogram ----------------
__global__ void hist_kernel(const int* __restrict__ src, const int* __restrict__ dst,
                            int* cnt_out, int* cnt_in, int E) {
    int e = blockIdx.x * 256 + threadIdx.x;
    if (e < E) {
        atomicAdd(&cnt_out[src[e]], 1);
        atomicAdd(&cnt_in[dst[e]], 1);
    }
}

// ---------------- exclusive scan of cnt_in -> row_start (single block) ----------------
__global__ __launch_bounds__(1024) void scan_kernel(const int* __restrict__ cnt_in,
                                                    int* __restrict__ row_start, int N) {
    __shared__ int part[1024];
    int t = threadIdx.x;
    int chunk = (N + 1023) / 1024;
    int beg = t * chunk;
    int end = min(beg + chunk, N);
    int s = 0;
    for (int i = beg; i < end; ++i) s += cnt_in[i];
    part[t] = s;
    __syncthreads();
    for (int off = 1; off < 1024; off *= 2) {
        int v = (t >= off) ? part[t - off] : 0;
        __syncthreads();
        part[t] += v;
        __syncthreads();
    }
    int pre = (t == 0) ? 0 : part[t - 1];
    for (int i = beg; i < end; ++i) { row_start[i] = pre; pre += cnt_in[i]; }
    if (t == 1023) row_start[N] = part[1023];
}

// ---------------- per-node setup: cursor copy + inv-sqrt degrees ----------------
__global__ void node_setup(const int* __restrict__ cnt_in, const int* __restrict__ cnt_out,
                           const int* __restrict__ row_start, int* __restrict__ cursor,
                           float* __restrict__ degI_is, float* __restrict__ degO_is, int N) {
    int n = blockIdx.x * 256 + threadIdx.x;
    if (n < N) {
        cursor[n] = row_start[n];
        degI_is[n] = rsqrtf((float)max(cnt_in[n], 1));
        degO_is[n] = rsqrtf((float)max(cnt_out[n], 1));
    }
}

// ---------------- CSR fill: csr_src[slot] = src[e] for edges grouped by dst ----------------
__global__ void fill_kernel(const int* __restrict__ src, const int* __restrict__ dst,
                            int* __restrict__ cursor, int* __restrict__ csr_src, int E) {
    int e = blockIdx.x * 256 + threadIdx.x;
    if (e < E) {
        int slot = atomicAdd(&cursor[dst[e]], 1);
        csr_src[slot] = src[e];
    }
}

// ---------------- staged-LDS GEMM: out[N x 96] = (rowScale? diag(rowScale):I) * A[N x K] @ W[K x 96] (+bias) ----------------
__global__ __launch_bounds__(192) void gemm96(const float* __restrict__ A, int K,
                                              const float* __restrict__ W,
                                              const float* __restrict__ bias,
                                              const float* __restrict__ rowScale,
                                              float* __restrict__ out, int N) {
    __shared__ float A_lds[64 * 36];
    __shared__ float W_lds[32 * 96];
    const int t = threadIdx.x;
    const int row0 = blockIdx.x * 64;
    const int tcol = t % 24;
    const int trow = t / 24;
    float acc[8][4];
#pragma unroll
    for (int i = 0; i < 8; ++i)
#pragma unroll
        for (int j = 0; j < 4; ++j) acc[i][j] = 0.f;

    for (int k0 = 0; k0 < K; k0 += 32) {
        for (int i = t; i < 32 * 24; i += 192) {
            ((float4*)W_lds)[i] = ((const float4*)W)[(size_t)k0 * 24 + i];
        }
        for (int i = t; i < 64 * 8; i += 192) {
            int r = i / 8, kk = i % 8;
            int gr = row0 + r;
            float4 v = make_float4(0.f, 0.f, 0.f, 0.f);
            if (gr < N) {
                v = *((const float4*)(A + (size_t)gr * K + k0 + kk * 4));
                if (rowScale) {
                    float s = rowScale[gr];
                    v.x *= s; v.y *= s; v.z *= s; v.w *= s;
                }
            }
            *((float4*)(A_lds + r * 36 + kk * 4)) = v;
        }
        __syncthreads();
#pragma unroll
        for (int kk4 = 0; kk4 < 8; ++kk4) {
            float4 a[8];
#pragma unroll
            for (int i = 0; i < 8; ++i)
                a[i] = *((const float4*)(A_lds + (trow + 8 * i) * 36 + kk4 * 4));
#pragma unroll
            for (int kk = 0; kk < 4; ++kk) {
                float wv[4];
#pragma unroll
                for (int j = 0; j < 4; ++j)
                    wv[j] = W_lds[(kk4 * 4 + kk) * 96 + tcol + 24 * j];
#pragma unroll
                for (int i = 0; i < 8; ++i) {
                    float av = (kk == 0) ? a[i].x : (kk == 1) ? a[i].y : (kk == 2) ? a[i].z : a[i].w;
#pragma unroll
                    for (int j = 0; j < 4; ++j) acc[i][j] = fmaf(av, wv[j], acc[i][j]);
                }
            }
        }
        __syncthreads();
    }
#pragma unroll
    for (int j = 0; j < 4; ++j) {
        int c = tcol + 24 * j;
        float b = bias ? bias[c] : 0.f;
#pragma unroll
        for (int i = 0; i < 8; ++i) {
            int gr = row0 + trow + 8 * i;
            if (gr < N) out[(size_t)gr * 96 + c] = acc[i][j] + b;
        }
    }
}

// ---------------- GraphConv aggregate, float4 per thread, edge loop unrolled x4 ----------------
// thread = (node, 4-feature chunk): 24 threads/node, 4 outstanding 16B gathers.
__global__ __launch_bounds__(192) void gc_agg(const float* __restrict__ hW,
                                              const int* __restrict__ row_start,
                                              const int* __restrict__ csr_src,
                                              const float* __restrict__ degI_is,
                                              const float* __restrict__ bias,
                                              float* __restrict__ hout, int N) {
    int tid = blockIdx.x * 192 + threadIdx.x;
    int n = tid / 24;
    int c = (tid % 24) * 4;
    if (n >= N) return;
    int beg = row_start[n], end = row_start[n + 1];
    float4 s = make_float4(0.f, 0.f, 0.f, 0.f);
    int e = beg;
    for (; e + 4 <= end; e += 4) {
        int i0 = csr_src[e], i1 = csr_src[e + 1], i2 = csr_src[e + 2], i3 = csr_src[e + 3];
        float4 v0 = *(const float4*)(hW + (size_t)i0 * 96 + c);
        float4 v1 = *(const float4*)(hW + (size_t)i1 * 96 + c);
        float4 v2 = *(const float4*)(hW + (size_t)i2 * 96 + c);
        float4 v3 = *(const float4*)(hW + (size_t)i3 * 96 + c);
        s.x += (v0.x + v1.x) + (v2.x + v3.x);
        s.y += (v0.y + v1.y) + (v2.y + v3.y);
        s.z += (v0.z + v1.z) + (v2.z + v3.z);
        s.w += (v0.w + v1.w) + (v2.w + v3.w);
    }
    for (; e < end; ++e) {
        int i0 = csr_src[e];
        float4 v0 = *(const float4*)(hW + (size_t)i0 * 96 + c);
        s.x += v0.x; s.y += v0.y; s.z += v0.z; s.w += v0.w;
    }
    float dn = degI_is[n];
    float4 b = *(const float4*)(bias + c);
    float4 o;
    o.x = fmaxf(fmaf(s.x, dn, b.x), 0.f);
    o.y = fmaxf(fmaf(s.y, dn, b.y), 0.f);
    o.z = fmaxf(fmaf(s.z, dn, b.z), 0.f);
    o.w = fmaxf(fmaf(s.w, dn, b.w), 0.f);
    *(float4*)(hout + (size_t)n * 96 + c) = o;
}

// ---------------- GATv2 fused attention+aggregate, branch-free online softmax, unroll x2 ----------------
__global__ __launch_bounds__(256) void gat_agg(const float* __restrict__ fs,
                                               const float* __restrict__ fd,
                                               const float* __restrict__ attn,
                                               const int* __restrict__ row_start,
                                               const int* __restrict__ csr_src,
                                               float* __restrict__ hout, int N) {
    int tid = blockIdx.x * 256 + threadIdx.x;
    int n = tid >> 3, hd = tid & 7;
    if (n >= N) return;
    float att[12], fdv[12];
    {
        const float4* ap = (const float4*)(attn + hd * 12);
        float4 a0 = ap[0], a1 = ap[1], a2 = ap[2];
        att[0]=a0.x; att[1]=a0.y; att[2]=a0.z; att[3]=a0.w;
        att[4]=a1.x; att[5]=a1.y; att[6]=a1.z; att[7]=a1.w;
        att[8]=a2.x; att[9]=a2.y; att[10]=a2.z; att[11]=a2.w;
        const float4* dp = (const float4*)(fd + (size_t)n * 96 + hd * 12);
        float4 d0 = dp[0], d1 = dp[1], d2 = dp[2];
        fdv[0]=d0.x; fdv[1]=d0.y; fdv[2]=d0.z; fdv[3]=d0.w;
        fdv[4]=d1.x; fdv[5]=d1.y; fdv[6]=d1.z; fdv[7]=d1.w;
        fdv[8]=d2.x; fdv[9]=d2.y; fdv[10]=d2.z; fdv[11]=d2.w;
    }
    int beg = row_start[n], end = row_start[n + 1];
    float m = -3.0e38f, den = 0.f;
    float acc[12];
#pragma unroll
    for (int d = 0; d < 12; ++d) acc[d] = 0.f;

    auto process = [&](float4 s0, float4 s1, float4 s2) {
        float fsv[12];
        fsv[0]=s0.x; fsv[1]=s0.y; fsv[2]=s0.z; fsv[3]=s0.w;
        fsv[4]=s1.x; fsv[5]=s1.y; fsv[6]=s1.z; fsv[7]=s1.w;
        fsv[8]=s2.x; fsv[9]=s2.y; fsv[10]=s2.z; fsv[11]=s2.w;
        float logit = 0.f;
#pragma unroll
        for (int d = 0; d < 12; ++d) {
            float u = fsv[d] + fdv[d];
            u = u > 0.f ? u : 0.2f * u;
            logit = fmaf(u, att[d], logit);
        }
        float nm = fmaxf(m, logit);
        float cc = __expf(m - nm);       // ==0 on first edge (m=-3e38)
        float w  = __expf(logit - nm);
        den = fmaf(den, cc, w);
#pragma unroll
        for (int d = 0; d < 12; ++d) acc[d] = fmaf(acc[d], cc, w * fsv[d]);
        m = nm;
    };

    int e = beg;
    for (; e + 2 <= end; e += 2) {
        int i0 = csr_src[e], i1 = csr_src[e + 1];
        const float4* p0 = (const float4*)(fs + (size_t)i0 * 96 + hd * 12);
        const float4* p1 = (const float4*)(fs + (size_t)i1 * 96 + hd * 12);
        float4 a0 = p0[0], a1 = p0[1], a2 = p0[2];
        float4 b0 = p1[0], b1 = p1[1], b2 = p1[2];
        process(a0, a1, a2);
        process(b0, b1, b2);
    }
    for (; e < end; ++e) {
        int i0 = csr_src[e];
        const float4* p0 = (const float4*)(fs + (size_t)i0 * 96 + hd * 12);
        process(p0[0], p0[1], p0[2]);
    }
    float inv = den > 0.f ? 1.f / den : 0.f;
    float* op = hout + (size_t)n * 96 + hd * 12;
#pragma unroll
    for (int d = 0; d < 12; ++d) op[d] = fmaxf(acc[d] * inv, 0.f);
}

// ---------------- per-graph max readout (values >= 0, hg zero-inited) ----------------
__global__ void readout_max(const float* __restrict__ h, const int* __restrict__ graph_id,
                            float* __restrict__ hg, int N) {
    int tid = blockIdx.x * 256 + threadIdx.x;
    if (tid >= N * 96) return;
    int n = tid / 96, f = tid % 96;
    int g = graph_id[n];
    float v = h[tid];
    atomicMax((int*)&hg[(size_t)g * 96 + f], __float_as_int(v));
}

// ---------------- classifier MLP: one block per graph ----------------
__global__ __launch_bounds__(96) void mlp_kernel(const float* __restrict__ hg,
                                                 const float* __restrict__ Wc1, const float* __restrict__ bc1,
                                                 const float* __restrict__ Wc2, const float* __restrict__ bc2,
                                                 const float* __restrict__ Wc3, const float* __restrict__ bc3,
                                                 float* __restrict__ out) {
    int g = blockIdx.x;
    int t = threadIdx.x;
    __shared__ float z0[96], z1[96], z2[48];
    z0[t] = hg[(size_t)g * 96 + t];
    __syncthreads();
    float s = bc1[t];
    for (int k = 0; k < 96; ++k) s = fmaf(z0[k], Wc1[k * 96 + t], s);
    z1[t] = fmaxf(s, 0.f);
    __syncthreads();
    if (t < 48) {
        float s2 = bc2[t];
        for (int k = 0; k < 96; ++k) s2 = fmaf(z1[k], Wc2[k * 48 + t], s2);
        z2[t] = fmaxf(s2, 0.f);
    }
    __syncthreads();
    if (t < 10) {
        float s3 = bc3[t];
        for (int k = 0; k < 48; ++k) s3 = fmaf(z2[k], Wc3[k * 10 + t], s3);
        out[(size_t)g * 10 + t] = s3;
    }
}

extern "C" void kernel_launch(void* const* d_in, const int* in_sizes, int n_in,
                              void* d_out, int out_size, void* d_ws, size_t ws_size,
                              hipStream_t stream) {
    const float* x        = (const float*)d_in[0];
    const int*   src      = (const int*)d_in[1];
    const int*   dst      = (const int*)d_in[2];
    const int*   graph_id = (const int*)d_in[3];
    const float* W1  = (const float*)d_in[4];
    const float* b1  = (const float*)d_in[5];
    const float* W2  = (const float*)d_in[6];
    const float* b2  = (const float*)d_in[7];
    const float* Ws  = (const float*)d_in[8];
    const float* bs  = (const float*)d_in[9];
    const float* Wd  = (const float*)d_in[10];
    const float* bd  = (const float*)d_in[11];
    const float* attn = (const float*)d_in[12];
    const float* Wc1 = (const float*)d_in[13];
    const float* bc1 = (const float*)d_in[14];
    const float* Wc2 = (const float*)d_in[15];
    const float* bc2 = (const float*)d_in[16];
    const float* Wc3 = (const float*)d_in[17];
    const float* bc3 = (const float*)d_in[18];
    float* out = (float*)d_out;

    char* ws = (char*)d_ws;
    size_t off = 0;
    auto alloc = [&](size_t bytes) {
        char* p = ws + off;
        off = (off + bytes + 255) & ~(size_t)255;
        return p;
    };
    int*   cnt_in    = (int*)alloc(Nn * 4);
    int*   cnt_out   = (int*)alloc(Nn * 4);
    int*   row_start = (int*)alloc((Nn + 1) * 4);
    int*   cursor    = (int*)alloc(Nn * 4);
    int*   csr_src   = (int*)alloc(Ee * 4);
    float* degI_is   = (float*)alloc(Nn * 4);
    float* degO_is   = (float*)alloc(Nn * 4);
    float* bufH      = (float*)alloc((size_t)Nn * 96 * 4);
    float* bufT      = (float*)alloc((size_t)Nn * 96 * 4);
    float* bufFd     = (float*)alloc((size_t)Nn * 96 * 4);
    float* hg        = (float*)alloc(GG * 96 * 4);

    hipMemsetAsync(cnt_in, 0, Nn * 4, stream);
    hipMemsetAsync(cnt_out, 0, Nn * 4, stream);
    hipMemsetAsync(hg, 0, GG * 96 * 4, stream);

    int eb = (Ee + 255) / 256;
    hist_kernel<<<eb, 256, 0, stream>>>(src, dst, cnt_out, cnt_in, Ee);
    scan_kernel<<<1, 1024, 0, stream>>>(cnt_in, row_start, Nn);
    node_setup<<<(Nn + 255) / 256, 256, 0, stream>>>(cnt_in, cnt_out, row_start, cursor,
                                                     degI_is, degO_is, Nn);
    fill_kernel<<<eb, 256, 0, stream>>>(src, dst, cursor, csr_src, Ee);

    int gemm_blocks = (Nn + 63) / 64;
    int agg_blocks  = (Nn * 24 + 191) / 192;
    int gat_blocks  = (Nn * 8 + 255) / 256;

    // GraphConv 1: x[N,128] -> bufH
    gemm96<<<gemm_blocks, 192, 0, stream>>>(x, 128, W1, nullptr, degO_is, bufT, Nn);
    gc_agg<<<agg_blocks, 192, 0, stream>>>(bufT, row_start, csr_src, degI_is, b1, bufH, Nn);
    // GraphConv 2
    gemm96<<<gemm_blocks, 192, 0, stream>>>(bufH, 96, W2, nullptr, degO_is, bufT, Nn);
    gc_agg<<<agg_blocks, 192, 0, stream>>>(bufT, row_start, csr_src, degI_is, b2, bufH, Nn);

    // 3x GATv2
    for (int l = 0; l < 3; ++l) {
        const float* Wsl = Ws + (size_t)l * 96 * 96;
        const float* bsl = bs + (size_t)l * 96;
        const float* Wdl = Wd + (size_t)l * 96 * 96;
        const float* bdl = bd + (size_t)l * 96;
        const float* atl = attn + (size_t)l * 96;
        gemm96<<<gemm_blocks, 192, 0, stream>>>(bufH, 96, Wsl, bsl, nullptr, bufT, Nn);
        gemm96<<<gemm_blocks, 192, 0, stream>>>(bufH, 96, Wdl, bdl, nullptr, bufFd, Nn);
        gat_agg<<<gat_blocks, 256, 0, stream>>>(bufT, bufFd, atl, row_start, csr_src, bufH, Nn);
    }

    readout_max<<<(Nn * 96 + 255) / 256, 256, 0, stream>>>(bufH, graph_id, hg, Nn);
    mlp_kernel<<<GG, 96, 0, stream>>>(hg, Wc1, bc1, Wc2, bc2, Wc3, bc3, out);
}

// Round 3
// 717.944 us; speedup vs baseline: 1.2950x; 1.0800x over previous
//
#include <hip/hip_runtime.h>
#include <hip/hip_bf16.h>

#define Nn 50000
#define Ee 800000
#define INF_ 128
#define HIDF 96
#define HH 8
#define DD 12
#define GG 64
#define OUTF 10

#define SCAN_CHUNK 512
#define SCAN_BLOCKS ((Nn + SCAN_CHUNK - 1) / SCAN_CHUNK)   // 98

// ---------------- degree histogram ----------------
__global__ void hist_kernel(const int* __restrict__ src, const int* __restrict__ dst,
                            int* cnt_out, int* cnt_in, int E) {
    int e = blockIdx.x * 256 + threadIdx.x;
    if (e < E) {
        atomicAdd(&cnt_out[src[e]], 1);
        atomicAdd(&cnt_in[dst[e]], 1);
    }
}

// ---------------- hierarchical scan, stage 1: per-block scan + block sums ----------------
__global__ __launch_bounds__(256) void scan1_kernel(const int* __restrict__ cnt_in,
                                                    int* __restrict__ row_start,
                                                    int* __restrict__ blk_sum, int N) {
    __shared__ int part[256];
    int t = threadIdx.x;
    int base = blockIdx.x * SCAN_CHUNK;
    int i0 = base + 2 * t, i1 = i0 + 1;
    int a = (i0 < N) ? cnt_in[i0] : 0;
    int b = (i1 < N) ? cnt_in[i1] : 0;
    int s = a + b;
    part[t] = s;
    __syncthreads();
    for (int off = 1; off < 256; off <<= 1) {
        int v = (t >= off) ? part[t - off] : 0;
        __syncthreads();
        part[t] += v;
        __syncthreads();
    }
    int excl = part[t] - s;
    if (i0 < N) row_start[i0] = excl;
    if (i1 < N) row_start[i1] = excl + a;
    if (t == 255) blk_sum[blockIdx.x] = part[255];
}

// ---------------- stage 2: scan the 98 block sums (single tiny block) ----------------
__global__ __launch_bounds__(128) void scan2_kernel(const int* __restrict__ blk_sum,
                                                    int* __restrict__ blk_off,
                                                    int* __restrict__ row_start, int N) {
    __shared__ int part[128];
    int t = threadIdx.x;
    int v0 = (t < SCAN_BLOCKS) ? blk_sum[t] : 0;
    part[t] = v0;
    __syncthreads();
    for (int off = 1; off < 128; off <<= 1) {
        int v = (t >= off) ? part[t - off] : 0;
        __syncthreads();
        part[t] += v;
        __syncthreads();
    }
    blk_off[t] = part[t] - v0;
    if (t == 127) row_start[N] = part[127];
}

// ---------------- stage 3: add block offsets ----------------
__global__ __launch_bounds__(256) void scan3_kernel(int* __restrict__ row_start,
                                                    const int* __restrict__ blk_off, int N) {
    int t = threadIdx.x;
    int base = blockIdx.x * SCAN_CHUNK;
    int off = blk_off[blockIdx.x];
    int i0 = base + 2 * t, i1 = i0 + 1;
    if (i0 < N) row_start[i0] += off;
    if (i1 < N) row_start[i1] += off;
}

// ---------------- per-node setup: cursor copy + inv-sqrt degrees ----------------
__global__ void node_setup(const int* __restrict__ cnt_in, const int* __restrict__ cnt_out,
                           const int* __restrict__ row_start, int* __restrict__ cursor,
                           float* __restrict__ degI_is, float* __restrict__ degO_is, int N) {
    int n = blockIdx.x * 256 + threadIdx.x;
    if (n < N) {
        cursor[n] = row_start[n];
        degI_is[n] = rsqrtf((float)max(cnt_in[n], 1));
        degO_is[n] = rsqrtf((float)max(cnt_out[n], 1));
    }
}

// ---------------- CSR fill ----------------
__global__ void fill_kernel(const int* __restrict__ src, const int* __restrict__ dst,
                            int* __restrict__ cursor, int* __restrict__ csr_src, int E) {
    int e = blockIdx.x * 256 + threadIdx.x;
    if (e < E) {
        int slot = atomicAdd(&cursor[dst[e]], 1);
        csr_src[slot] = src[e];
    }
}

// ---------------- staged-LDS GEMM: out[N x 96] = diag(rowScale) * A[N x K] @ W[K x 96] (+bias) ----------------
__global__ __launch_bounds__(192) void gemm96(const float* __restrict__ A, int K,
                                              const float* __restrict__ W,
                                              const float* __restrict__ bias,
                                              const float* __restrict__ rowScale,
                                              float* __restrict__ out, int N) {
    __shared__ float A_lds[64 * 36];
    __shared__ float W_lds[32 * 96];
    const int t = threadIdx.x;
    const int row0 = blockIdx.x * 64;
    const int tcol = t % 24;
    const int trow = t / 24;
    float acc[8][4];
#pragma unroll
    for (int i = 0; i < 8; ++i)
#pragma unroll
        for (int j = 0; j < 4; ++j) acc[i][j] = 0.f;

    for (int k0 = 0; k0 < K; k0 += 32) {
        for (int i = t; i < 32 * 24; i += 192) {
            ((float4*)W_lds)[i] = ((const float4*)W)[(size_t)k0 * 24 + i];
        }
        for (int i = t; i < 64 * 8; i += 192) {
            int r = i / 8, kk = i % 8;
            int gr = row0 + r;
            float4 v = make_float4(0.f, 0.f, 0.f, 0.f);
            if (gr < N) {
                v = *((const float4*)(A + (size_t)gr * K + k0 + kk * 4));
                if (rowScale) {
                    float s = rowScale[gr];
                    v.x *= s; v.y *= s; v.z *= s; v.w *= s;
                }
            }
            *((float4*)(A_lds + r * 36 + kk * 4)) = v;
        }
        __syncthreads();
#pragma unroll
        for (int kk4 = 0; kk4 < 8; ++kk4) {
            float4 a[8];
#pragma unroll
            for (int i = 0; i < 8; ++i)
                a[i] = *((const float4*)(A_lds + (trow + 8 * i) * 36 + kk4 * 4));
#pragma unroll
            for (int kk = 0; kk < 4; ++kk) {
                float wv[4];
#pragma unroll
                for (int j = 0; j < 4; ++j)
                    wv[j] = W_lds[(kk4 * 4 + kk) * 96 + tcol + 24 * j];
#pragma unroll
                for (int i = 0; i < 8; ++i) {
                    float av = (kk == 0) ? a[i].x : (kk == 1) ? a[i].y : (kk == 2) ? a[i].z : a[i].w;
#pragma unroll
                    for (int j = 0; j < 4; ++j) acc[i][j] = fmaf(av, wv[j], acc[i][j]);
                }
            }
        }
        __syncthreads();
    }
#pragma unroll
    for (int j = 0; j < 4; ++j) {
        int c = tcol + 24 * j;
        float b = bias ? bias[c] : 0.f;
#pragma unroll
        for (int i = 0; i < 8; ++i) {
            int gr = row0 + trow + 8 * i;
            if (gr < N) out[(size_t)gr * 96 + c] = acc[i][j] + b;
        }
    }
}

// ---------------- dual GEMM: A read once, two weight sets, two outputs (K=96) ----------------
__global__ __launch_bounds__(192) void gemm96x2(const float* __restrict__ A,
                                                const float* __restrict__ W1_, const float* __restrict__ b1_,
                                                const float* __restrict__ W2_, const float* __restrict__ b2_,
                                                float* __restrict__ out1, float* __restrict__ out2, int N) {
    __shared__ float A_lds[64 * 36];
    __shared__ float W_lds[2 * 32 * 96];
    const int t = threadIdx.x;
    const int row0 = blockIdx.x * 64;
    const int tcol = t % 24;
    const int trow = t / 24;
    float acc1[8][4], acc2[8][4];
#pragma unroll
    for (int i = 0; i < 8; ++i)
#pragma unroll
        for (int j = 0; j < 4; ++j) { acc1[i][j] = 0.f; acc2[i][j] = 0.f; }

    for (int k0 = 0; k0 < 96; k0 += 32) {
        for (int i = t; i < 32 * 24; i += 192) {
            ((float4*)W_lds)[i] = ((const float4*)W1_)[(size_t)k0 * 24 + i];
            ((float4*)(W_lds + 32 * 96))[i] = ((const float4*)W2_)[(size_t)k0 * 24 + i];
        }
        for (int i = t; i < 64 * 8; i += 192) {
            int r = i / 8, kk = i % 8;
            int gr = row0 + r;
            float4 v = make_float4(0.f, 0.f, 0.f, 0.f);
            if (gr < N) v = *((const float4*)(A + (size_t)gr * 96 + k0 + kk * 4));
            *((float4*)(A_lds + r * 36 + kk * 4)) = v;
        }
        __syncthreads();
#pragma unroll
        for (int kk4 = 0; kk4 < 8; ++kk4) {
            float4 a[8];
#pragma unroll
            for (int i = 0; i < 8; ++i)
                a[i] = *((const float4*)(A_lds + (trow + 8 * i) * 36 + kk4 * 4));
#pragma unroll
            for (int kk = 0; kk < 4; ++kk) {
                float wv1[4], wv2[4];
#pragma unroll
                for (int j = 0; j < 4; ++j) {
                    wv1[j] = W_lds[(kk4 * 4 + kk) * 96 + tcol + 24 * j];
                    wv2[j] = W_lds[32 * 96 + (kk4 * 4 + kk) * 96 + tcol + 24 * j];
                }
#pragma unroll
                for (int i = 0; i < 8; ++i) {
                    float av = (kk == 0) ? a[i].x : (kk == 1) ? a[i].y : (kk == 2) ? a[i].z : a[i].w;
#pragma unroll
                    for (int j = 0; j < 4; ++j) {
                        acc1[i][j] = fmaf(av, wv1[j], acc1[i][j]);
                        acc2[i][j] = fmaf(av, wv2[j], acc2[i][j]);
                    }
                }
            }
        }
        __syncthreads();
    }
#pragma unroll
    for (int j = 0; j < 4; ++j) {
        int c = tcol + 24 * j;
        float bb1 = b1_[c], bb2 = b2_[c];
#pragma unroll
        for (int i = 0; i < 8; ++i) {
            int gr = row0 + trow + 8 * i;
            if (gr < N) {
                out1[(size_t)gr * 96 + c] = acc1[i][j] + bb1;
                out2[(size_t)gr * 96 + c] = acc2[i][j] + bb2;
            }
        }
    }
}

// ---------------- GraphConv aggregate, float4 per thread, edge loop unrolled x4 ----------------
__global__ __launch_bounds__(192) void gc_agg(const float* __restrict__ hW,
                                              const int* __restrict__ row_start,
                                              const int* __restrict__ csr_src,
                                              const float* __restrict__ degI_is,
                                              const float* __restrict__ bias,
                                              float* __restrict__ hout, int N) {
    int tid = blockIdx.x * 192 + threadIdx.x;
    int n = tid / 24;
    int c = (tid % 24) * 4;
    if (n >= N) return;
    int beg = row_start[n], end = row_start[n + 1];
    float4 s = make_float4(0.f, 0.f, 0.f, 0.f);
    int e = beg;
    for (; e + 4 <= end; e += 4) {
        int i0 = csr_src[e], i1 = csr_src[e + 1], i2 = csr_src[e + 2], i3 = csr_src[e + 3];
        float4 v0 = *(const float4*)(hW + (size_t)i0 * 96 + c);
        float4 v1 = *(const float4*)(hW + (size_t)i1 * 96 + c);
        float4 v2 = *(const float4*)(hW + (size_t)i2 * 96 + c);
        float4 v3 = *(const float4*)(hW + (size_t)i3 * 96 + c);
        s.x += (v0.x + v1.x) + (v2.x + v3.x);
        s.y += (v0.y + v1.y) + (v2.y + v3.y);
        s.z += (v0.z + v1.z) + (v2.z + v3.z);
        s.w += (v0.w + v1.w) + (v2.w + v3.w);
    }
    for (; e < end; ++e) {
        int i0 = csr_src[e];
        float4 v0 = *(const float4*)(hW + (size_t)i0 * 96 + c);
        s.x += v0.x; s.y += v0.y; s.z += v0.z; s.w += v0.w;
    }
    float dn = degI_is[n];
    float4 b = *(const float4*)(bias + c);
    float4 o;
    o.x = fmaxf(fmaf(s.x, dn, b.x), 0.f);
    o.y = fmaxf(fmaf(s.y, dn, b.y), 0.f);
    o.z = fmaxf(fmaf(s.z, dn, b.z), 0.f);
    o.w = fmaxf(fmaf(s.w, dn, b.w), 0.f);
    *(float4*)(hout + (size_t)n * 96 + c) = o;
}

// ---------------- GATv2 fused attention+aggregate, branch-free online softmax, unroll x4 ----------------
__global__ __launch_bounds__(256) void gat_agg(const float* __restrict__ fs,
                                               const float* __restrict__ fd,
                                               const float* __restrict__ attn,
                                               const int* __restrict__ row_start,
                                               const int* __restrict__ csr_src,
                                               float* __restrict__ hout, int N) {
    int tid = blockIdx.x * 256 + threadIdx.x;
    int n = tid >> 3, hd = tid & 7;
    if (n >= N) return;
    float att[12], fdv[12];
    {
        const float4* ap = (const float4*)(attn + hd * 12);
        float4 a0 = ap[0], a1 = ap[1], a2 = ap[2];
        att[0]=a0.x; att[1]=a0.y; att[2]=a0.z; att[3]=a0.w;
        att[4]=a1.x; att[5]=a1.y; att[6]=a1.z; att[7]=a1.w;
        att[8]=a2.x; att[9]=a2.y; att[10]=a2.z; att[11]=a2.w;
        const float4* dp = (const float4*)(fd + (size_t)n * 96 + hd * 12);
        float4 d0 = dp[0], d1 = dp[1], d2 = dp[2];
        fdv[0]=d0.x; fdv[1]=d0.y; fdv[2]=d0.z; fdv[3]=d0.w;
        fdv[4]=d1.x; fdv[5]=d1.y; fdv[6]=d1.z; fdv[7]=d1.w;
        fdv[8]=d2.x; fdv[9]=d2.y; fdv[10]=d2.z; fdv[11]=d2.w;
    }
    int beg = row_start[n], end = row_start[n + 1];
    float m = -3.0e38f, den = 0.f;
    float acc[12];
#pragma unroll
    for (int d = 0; d < 12; ++d) acc[d] = 0.f;

    auto process = [&](const float4& s0, const float4& s1, const float4& s2) {
        float fsv[12];
        fsv[0]=s0.x; fsv[1]=s0.y; fsv[2]=s0.z; fsv[3]=s0.w;
        fsv[4]=s1.x; fsv[5]=s1.y; fsv[6]=s1.z; fsv[7]=s1.w;
        fsv[8]=s2.x; fsv[9]=s2.y; fsv[10]=s2.z; fsv[11]=s2.w;
        float logit = 0.f;
#pragma unroll
        for (int d = 0; d < 12; ++d) {
            float u = fsv[d] + fdv[d];
            u = u > 0.f ? u : 0.2f * u;
            logit = fmaf(u, att[d], logit);
        }
        float nm = fmaxf(m, logit);
        float cc = __expf(m - nm);
        float w  = __expf(logit - nm);
        den = fmaf(den, cc, w);
#pragma unroll
        for (int d = 0; d < 12; ++d) acc[d] = fmaf(acc[d], cc, w * fsv[d]);
        m = nm;
    };

    int e = beg;
    for (; e + 4 <= end; e += 4) {
        int i0 = csr_src[e], i1 = csr_src[e + 1], i2 = csr_src[e + 2], i3 = csr_src[e + 3];
        const float4* p0 = (const float4*)(fs + (size_t)i0 * 96 + hd * 12);
        const float4* p1 = (const float4*)(fs + (size_t)i1 * 96 + hd * 12);
        const float4* p2 = (const float4*)(fs + (size_t)i2 * 96 + hd * 12);
        const float4* p3 = (const float4*)(fs + (size_t)i3 * 96 + hd * 12);
        float4 a0 = p0[0], a1 = p0[1], a2 = p0[2];
        float4 b0 = p1[0], b1 = p1[1], b2 = p1[2];
        float4 c0 = p2[0], c1 = p2[1], c2 = p2[2];
        float4 d0 = p3[0], d1 = p3[1], d2 = p3[2];
        process(a0, a1, a2);
        process(b0, b1, b2);
        process(c0, c1, c2);
        process(d0, d1, d2);
    }
    for (; e < end; ++e) {
        int i0 = csr_src[e];
        const float4* p0 = (const float4*)(fs + (size_t)i0 * 96 + hd * 12);
        float4 a0 = p0[0], a1 = p0[1], a2 = p0[2];
        process(a0, a1, a2);
    }
    float inv = den > 0.f ? 1.f / den : 0.f;
    float* op = hout + (size_t)n * 96 + hd * 12;
#pragma unroll
    for (int d = 0; d < 12; ++d) op[d] = fmaxf(acc[d] * inv, 0.f);
}

// ---------------- per-graph max readout ----------------
__global__ void readout_max(const float* __restrict__ h, const int* __restrict__ graph_id,
                            float* __restrict__ hg, int N) {
    int tid = blockIdx.x * 256 + threadIdx.x;
    if (tid >= N * 96) return;
    int n = tid / 96, f = tid % 96;
    int g = graph_id[n];
    float v = h[tid];
    atomicMax((int*)&hg[(size_t)g * 96 + f], __float_as_int(v));
}

// ---------------- classifier MLP: one block per graph ----------------
__global__ __launch_bounds__(96) void mlp_kernel(const float* __restrict__ hg,
                                                 const float* __restrict__ Wc1, const float* __restrict__ bc1,
                                                 const float* __restrict__ Wc2, const float* __restrict__ bc2,
                                                 const float* __restrict__ Wc3, const float* __restrict__ bc3,
                                                 float* __restrict__ out) {
    int g = blockIdx.x;
    int t = threadIdx.x;
    __shared__ float z0[96], z1[96], z2[48];
    z0[t] = hg[(size_t)g * 96 + t];
    __syncthreads();
    float s = bc1[t];
    for (int k = 0; k < 96; ++k) s = fmaf(z0[k], Wc1[k * 96 + t], s);
    z1[t] = fmaxf(s, 0.f);
    __syncthreads();
    if (t < 48) {
        float s2 = bc2[t];
        for (int k = 0; k < 96; ++k) s2 = fmaf(z1[k], Wc2[k * 48 + t], s2);
        z2[t] = fmaxf(s2, 0.f);
    }
    __syncthreads();
    if (t < 10) {
        float s3 = bc3[t];
        for (int k = 0; k < 48; ++k) s3 = fmaf(z2[k], Wc3[k * 10 + t], s3);
        out[(size_t)g * 10 + t] = s3;
    }
}

extern "C" void kernel_launch(void* const* d_in, const int* in_sizes, int n_in,
                              void* d_out, int out_size, void* d_ws, size_t ws_size,
                              hipStream_t stream) {
    const float* x        = (const float*)d_in[0];
    const int*   src      = (const int*)d_in[1];
    const int*   dst      = (const int*)d_in[2];
    const int*   graph_id = (const int*)d_in[3];
    const float* W1  = (const float*)d_in[4];
    const float* b1  = (const float*)d_in[5];
    const float* W2  = (const float*)d_in[6];
    const float* b2  = (const float*)d_in[7];
    const float* Ws  = (const float*)d_in[8];
    const float* bs  = (const float*)d_in[9];
    const float* Wd  = (const float*)d_in[10];
    const float* bd  = (const float*)d_in[11];
    const float* attn = (const float*)d_in[12];
    const float* Wc1 = (const float*)d_in[13];
    const float* bc1 = (const float*)d_in[14];
    const float* Wc2 = (const float*)d_in[15];
    const float* bc2 = (const float*)d_in[16];
    const float* Wc3 = (const float*)d_in[17];
    const float* bc3 = (const float*)d_in[18];
    float* out = (float*)d_out;

    char* ws = (char*)d_ws;
    size_t off = 0;
    auto alloc = [&](size_t bytes) {
        char* p = ws + off;
        off = (off + bytes + 255) & ~(size_t)255;
        return p;
    };
    int*   cnt_in    = (int*)alloc(Nn * 4);
    int*   cnt_out   = (int*)alloc(Nn * 4);
    int*   row_start = (int*)alloc((Nn + 1) * 4);
    int*   cursor    = (int*)alloc(Nn * 4);
    int*   csr_src   = (int*)alloc(Ee * 4);
    float* degI_is   = (float*)alloc(Nn * 4);
    float* degO_is   = (float*)alloc(Nn * 4);
    float* bufH      = (float*)alloc((size_t)Nn * 96 * 4);
    float* bufT      = (float*)alloc((size_t)Nn * 96 * 4);
    float* bufFd     = (float*)alloc((size_t)Nn * 96 * 4);
    float* hg        = (float*)alloc(GG * 96 * 4);
    int*   blk_sum   = (int*)alloc(128 * 4);
    int*   blk_off   = (int*)alloc(128 * 4);

    hipMemsetAsync(cnt_in, 0, Nn * 4, stream);
    hipMemsetAsync(cnt_out, 0, Nn * 4, stream);
    hipMemsetAsync(hg, 0, GG * 96 * 4, stream);

    int eb = (Ee + 255) / 256;
    hist_kernel<<<eb, 256, 0, stream>>>(src, dst, cnt_out, cnt_in, Ee);
    scan1_kernel<<<SCAN_BLOCKS, 256, 0, stream>>>(cnt_in, row_start, blk_sum, Nn);
    scan2_kernel<<<1, 128, 0, stream>>>(blk_sum, blk_off, row_start, Nn);
    scan3_kernel<<<SCAN_BLOCKS, 256, 0, stream>>>(row_start, blk_off, Nn);
    node_setup<<<(Nn + 255) / 256, 256, 0, stream>>>(cnt_in, cnt_out, row_start, cursor,
                                                     degI_is, degO_is, Nn);
    fill_kernel<<<eb, 256, 0, stream>>>(src, dst, cursor, csr_src, Ee);

    int gemm_blocks = (Nn + 63) / 64;
    int agg_blocks  = (Nn * 24 + 191) / 192;
    int gat_blocks  = (Nn * 8 + 255) / 256;

    // GraphConv 1: x[N,128] -> bufH
    gemm96<<<gemm_blocks, 192, 0, stream>>>(x, 128, W1, nullptr, degO_is, bufT, Nn);
    gc_agg<<<agg_blocks, 192, 0, stream>>>(bufT, row_start, csr_src, degI_is, b1, bufH, Nn);
    // GraphConv 2
    gemm96<<<gemm_blocks, 192, 0, stream>>>(bufH, 96, W2, nullptr, degO_is, bufT, Nn);
    gc_agg<<<agg_blocks, 192, 0, stream>>>(bufT, row_start, csr_src, degI_is, b2, bufH, Nn);

    // 3x GATv2: fused dual GEMM (fs,fd) then fused attention+aggregate
    for (int l = 0; l < 3; ++l) {
        const float* Wsl = Ws + (size_t)l * 96 * 96;
        const float* bsl = bs + (size_t)l * 96;
        const float* Wdl = Wd + (size_t)l * 96 * 96;
        const float* bdl = bd + (size_t)l * 96;
        const float* atl = attn + (size_t)l * 96;
        gemm96x2<<<gemm_blocks, 192, 0, stream>>>(bufH, Wsl, bsl, Wdl, bdl, bufT, bufFd, Nn);
        gat_agg<<<gat_blocks, 256, 0, stream>>>(bufT, bufFd, atl, row_start, csr_src, bufH, Nn);
    }

    readout_max<<<(Nn * 96 + 255) / 256, 256, 0, stream>>>(bufH, graph_id, hg, Nn);
    mlp_kernel<<<GG, 96, 0, stream>>>(hg, Wc1, bc1, Wc2, bc2, Wc3, bc3, out);
}

// Round 4
// 679.115 us; speedup vs baseline: 1.3691x; 1.0572x over previous
//
#include <hip/hip_runtime.h>
#include <hip/hip_bf16.h>

#define Nn 50000
#define Ee 800000
#define INF_ 128
#define HIDF 96
#define HH 8
#define DD 12
#define GG 64
#define OUTF 10

#define SCAN_CHUNK 512
#define SCAN_BLOCKS ((Nn + SCAN_CHUNK - 1) / SCAN_CHUNK)   // 98
#define RB 128   // readout partial blocks

// ---------------- degree histogram; also emits per-edge CSR slot ----------------
__global__ void hist_kernel(const int* __restrict__ src, const int* __restrict__ dst,
                            int* cnt_out, int* cnt_in, int* __restrict__ edge_slot, int E) {
    int e = blockIdx.x * 256 + threadIdx.x;
    if (e < E) {
        atomicAdd(&cnt_out[src[e]], 1);
        edge_slot[e] = atomicAdd(&cnt_in[dst[e]], 1);
    }
}

// ---------------- hierarchical scan, stage 1 ----------------
__global__ __launch_bounds__(256) void scan1_kernel(const int* __restrict__ cnt_in,
                                                    int* __restrict__ row_start,
                                                    int* __restrict__ blk_sum, int N) {
    __shared__ int part[256];
    int t = threadIdx.x;
    int base = blockIdx.x * SCAN_CHUNK;
    int i0 = base + 2 * t, i1 = i0 + 1;
    int a = (i0 < N) ? cnt_in[i0] : 0;
    int b = (i1 < N) ? cnt_in[i1] : 0;
    int s = a + b;
    part[t] = s;
    __syncthreads();
    for (int off = 1; off < 256; off <<= 1) {
        int v = (t >= off) ? part[t - off] : 0;
        __syncthreads();
        part[t] += v;
        __syncthreads();
    }
    int excl = part[t] - s;
    if (i0 < N) row_start[i0] = excl;
    if (i1 < N) row_start[i1] = excl + a;
    if (t == 255) blk_sum[blockIdx.x] = part[255];
}

// ---------------- stage 2: scan block sums ----------------
__global__ __launch_bounds__(128) void scan2_kernel(const int* __restrict__ blk_sum,
                                                    int* __restrict__ blk_off,
                                                    int* __restrict__ row_start, int N) {
    __shared__ int part[128];
    int t = threadIdx.x;
    int v0 = (t < SCAN_BLOCKS) ? blk_sum[t] : 0;
    part[t] = v0;
    __syncthreads();
    for (int off = 1; off < 128; off <<= 1) {
        int v = (t >= off) ? part[t - off] : 0;
        __syncthreads();
        part[t] += v;
        __syncthreads();
    }
    blk_off[t] = part[t] - v0;
    if (t == 127) row_start[N] = part[127];
}

// ---------------- stage 3: add block offsets ----------------
__global__ __launch_bounds__(256) void scan3_kernel(int* __restrict__ row_start,
                                                    const int* __restrict__ blk_off, int N) {
    int t = threadIdx.x;
    int base = blockIdx.x * SCAN_CHUNK;
    int off = blk_off[blockIdx.x];
    int i0 = base + 2 * t, i1 = i0 + 1;
    if (i0 < N) row_start[i0] += off;
    if (i1 < N) row_start[i1] += off;
}

// ---------------- per-node setup: inv-sqrt degrees ----------------
__global__ void node_setup(const int* __restrict__ cnt_in, const int* __restrict__ cnt_out,
                           float* __restrict__ degI_is, float* __restrict__ degO_is, int N) {
    int n = blockIdx.x * 256 + threadIdx.x;
    if (n < N) {
        degI_is[n] = rsqrtf((float)max(cnt_in[n], 1));
        degO_is[n] = rsqrtf((float)max(cnt_out[n], 1));
    }
}

// ---------------- CSR fill (atomic-free: slot from hist) ----------------
__global__ void fill_kernel(const int* __restrict__ src, const int* __restrict__ dst,
                            const int* __restrict__ row_start, const int* __restrict__ edge_slot,
                            int* __restrict__ csr_src, int E) {
    int e = blockIdx.x * 256 + threadIdx.x;
    if (e < E) {
        csr_src[row_start[dst[e]] + edge_slot[e]] = src[e];
    }
}

// ---------------- staged-LDS GEMM: out[N x 96] = diag(rowScale) * A[N x K] @ W[K x 96] (+bias) ----------------
// thread owns 4 CONTIGUOUS output columns (tcol*4..+3): float4 W reads + float4 C stores.
__global__ __launch_bounds__(192) void gemm96(const float* __restrict__ A, int K,
                                              const float* __restrict__ W,
                                              const float* __restrict__ bias,
                                              const float* __restrict__ rowScale,
                                              float* __restrict__ out, int N) {
    __shared__ float A_lds[64 * 36];
    __shared__ float W_lds[32 * 96];
    const int t = threadIdx.x;
    const int row0 = blockIdx.x * 64;
    const int tcol = t % 24;
    const int trow = t / 24;
    float acc[8][4];
#pragma unroll
    for (int i = 0; i < 8; ++i)
#pragma unroll
        for (int j = 0; j < 4; ++j) acc[i][j] = 0.f;

    for (int k0 = 0; k0 < K; k0 += 32) {
        for (int i = t; i < 32 * 24; i += 192) {
            ((float4*)W_lds)[i] = ((const float4*)W)[(size_t)k0 * 24 + i];
        }
        for (int i = t; i < 64 * 8; i += 192) {
            int r = i / 8, kk = i % 8;
            int gr = row0 + r;
            float4 v = make_float4(0.f, 0.f, 0.f, 0.f);
            if (gr < N) {
                v = *((const float4*)(A + (size_t)gr * K + k0 + kk * 4));
                if (rowScale) {
                    float s = rowScale[gr];
                    v.x *= s; v.y *= s; v.z *= s; v.w *= s;
                }
            }
            *((float4*)(A_lds + r * 36 + kk * 4)) = v;
        }
        __syncthreads();
#pragma unroll
        for (int kk4 = 0; kk4 < 8; ++kk4) {
            float4 a[8];
#pragma unroll
            for (int i = 0; i < 8; ++i)
                a[i] = *((const float4*)(A_lds + (trow + 8 * i) * 36 + kk4 * 4));
#pragma unroll
            for (int kk = 0; kk < 4; ++kk) {
                float4 wv = *((const float4*)(W_lds + (kk4 * 4 + kk) * 96 + tcol * 4));
#pragma unroll
                for (int i = 0; i < 8; ++i) {
                    float av = (kk == 0) ? a[i].x : (kk == 1) ? a[i].y : (kk == 2) ? a[i].z : a[i].w;
                    acc[i][0] = fmaf(av, wv.x, acc[i][0]);
                    acc[i][1] = fmaf(av, wv.y, acc[i][1]);
                    acc[i][2] = fmaf(av, wv.z, acc[i][2]);
                    acc[i][3] = fmaf(av, wv.w, acc[i][3]);
                }
            }
        }
        __syncthreads();
    }
    float4 b4 = bias ? *((const float4*)(bias + tcol * 4)) : make_float4(0.f, 0.f, 0.f, 0.f);
#pragma unroll
    for (int i = 0; i < 8; ++i) {
        int gr = row0 + trow + 8 * i;
        if (gr < N) {
            float4 o = make_float4(acc[i][0] + b4.x, acc[i][1] + b4.y,
                                   acc[i][2] + b4.z, acc[i][3] + b4.w);
            *((float4*)(out + (size_t)gr * 96 + tcol * 4)) = o;
        }
    }
}

// ---------------- dual GEMM: A read once, two weight sets, two outputs (K=96) ----------------
__global__ __launch_bounds__(192) void gemm96x2(const float* __restrict__ A,
                                                const float* __restrict__ W1_, const float* __restrict__ b1_,
                                                const float* __restrict__ W2_, const float* __restrict__ b2_,
                                                float* __restrict__ out1, float* __restrict__ out2, int N) {
    __shared__ float A_lds[64 * 36];
    __shared__ float W_lds[2 * 32 * 96];
    const int t = threadIdx.x;
    const int row0 = blockIdx.x * 64;
    const int tcol = t % 24;
    const int trow = t / 24;
    float acc1[8][4], acc2[8][4];
#pragma unroll
    for (int i = 0; i < 8; ++i)
#pragma unroll
        for (int j = 0; j < 4; ++j) { acc1[i][j] = 0.f; acc2[i][j] = 0.f; }

    for (int k0 = 0; k0 < 96; k0 += 32) {
        for (int i = t; i < 32 * 24; i += 192) {
            ((float4*)W_lds)[i] = ((const float4*)W1_)[(size_t)k0 * 24 + i];
            ((float4*)(W_lds + 32 * 96))[i] = ((const float4*)W2_)[(size_t)k0 * 24 + i];
        }
        for (int i = t; i < 64 * 8; i += 192) {
            int r = i / 8, kk = i % 8;
            int gr = row0 + r;
            float4 v = make_float4(0.f, 0.f, 0.f, 0.f);
            if (gr < N) v = *((const float4*)(A + (size_t)gr * 96 + k0 + kk * 4));
            *((float4*)(A_lds + r * 36 + kk * 4)) = v;
        }
        __syncthreads();
#pragma unroll
        for (int kk4 = 0; kk4 < 8; ++kk4) {
            float4 a[8];
#pragma unroll
            for (int i = 0; i < 8; ++i)
                a[i] = *((const float4*)(A_lds + (trow + 8 * i) * 36 + kk4 * 4));
#pragma unroll
            for (int kk = 0; kk < 4; ++kk) {
                float4 wv1 = *((const float4*)(W_lds + (kk4 * 4 + kk) * 96 + tcol * 4));
                float4 wv2 = *((const float4*)(W_lds + 32 * 96 + (kk4 * 4 + kk) * 96 + tcol * 4));
#pragma unroll
                for (int i = 0; i < 8; ++i) {
                    float av = (kk == 0) ? a[i].x : (kk == 1) ? a[i].y : (kk == 2) ? a[i].z : a[i].w;
                    acc1[i][0] = fmaf(av, wv1.x, acc1[i][0]);
                    acc1[i][1] = fmaf(av, wv1.y, acc1[i][1]);
                    acc1[i][2] = fmaf(av, wv1.z, acc1[i][2]);
                    acc1[i][3] = fmaf(av, wv1.w, acc1[i][3]);
                    acc2[i][0] = fmaf(av, wv2.x, acc2[i][0]);
                    acc2[i][1] = fmaf(av, wv2.y, acc2[i][1]);
                    acc2[i][2] = fmaf(av, wv2.z, acc2[i][2]);
                    acc2[i][3] = fmaf(av, wv2.w, acc2[i][3]);
                }
            }
        }
        __syncthreads();
    }
    float4 bb1 = *((const float4*)(b1_ + tcol * 4));
    float4 bb2 = *((const float4*)(b2_ + tcol * 4));
#pragma unroll
    for (int i = 0; i < 8; ++i) {
        int gr = row0 + trow + 8 * i;
        if (gr < N) {
            float4 o1 = make_float4(acc1[i][0] + bb1.x, acc1[i][1] + bb1.y,
                                    acc1[i][2] + bb1.z, acc1[i][3] + bb1.w);
            float4 o2 = make_float4(acc2[i][0] + bb2.x, acc2[i][1] + bb2.y,
                                    acc2[i][2] + bb2.z, acc2[i][3] + bb2.w);
            *((float4*)(out1 + (size_t)gr * 96 + tcol * 4)) = o1;
            *((float4*)(out2 + (size_t)gr * 96 + tcol * 4)) = o2;
        }
    }
}

// ---------------- GraphConv aggregate, float4 per thread, edge loop unrolled x4 ----------------
__global__ __launch_bounds__(192) void gc_agg(const float* __restrict__ hW,
                                              const int* __restrict__ row_start,
                                              const int* __restrict__ csr_src,
                                              const float* __restrict__ degI_is,
                                              const float* __restrict__ bias,
                                              float* __restrict__ hout, int N) {
    int tid = blockIdx.x * 192 + threadIdx.x;
    int n = tid / 24;
    int c = (tid % 24) * 4;
    if (n >= N) return;
    int beg = row_start[n], end = row_start[n + 1];
    float4 s = make_float4(0.f, 0.f, 0.f, 0.f);
    int e = beg;
    for (; e + 4 <= end; e += 4) {
        int i0 = csr_src[e], i1 = csr_src[e + 1], i2 = csr_src[e + 2], i3 = csr_src[e + 3];
        float4 v0 = *(const float4*)(hW + (size_t)i0 * 96 + c);
        float4 v1 = *(const float4*)(hW + (size_t)i1 * 96 + c);
        float4 v2 = *(const float4*)(hW + (size_t)i2 * 96 + c);
        float4 v3 = *(const float4*)(hW + (size_t)i3 * 96 + c);
        s.x += (v0.x + v1.x) + (v2.x + v3.x);
        s.y += (v0.y + v1.y) + (v2.y + v3.y);
        s.z += (v0.z + v1.z) + (v2.z + v3.z);
        s.w += (v0.w + v1.w) + (v2.w + v3.w);
    }
    for (; e < end; ++e) {
        int i0 = csr_src[e];
        float4 v0 = *(const float4*)(hW + (size_t)i0 * 96 + c);
        s.x += v0.x; s.y += v0.y; s.z += v0.z; s.w += v0.w;
    }
    float dn = degI_is[n];
    float4 b = *(const float4*)(bias + c);
    float4 o;
    o.x = fmaxf(fmaf(s.x, dn, b.x), 0.f);
    o.y = fmaxf(fmaf(s.y, dn, b.y), 0.f);
    o.z = fmaxf(fmaf(s.z, dn, b.z), 0.f);
    o.w = fmaxf(fmaf(s.w, dn, b.w), 0.f);
    *(float4*)(hout + (size_t)n * 96 + c) = o;
}

// ---------------- GATv2 fused attention+aggregate, branch-free online softmax, unroll x4 ----------------
__global__ __launch_bounds__(256) void gat_agg(const float* __restrict__ fs,
                                               const float* __restrict__ fd,
                                               const float* __restrict__ attn,
                                               const int* __restrict__ row_start,
                                               const int* __restrict__ csr_src,
                                               float* __restrict__ hout, int N) {
    int tid = blockIdx.x * 256 + threadIdx.x;
    int n = tid >> 3, hd = tid & 7;
    if (n >= N) return;
    float att[12], fdv[12];
    {
        const float4* ap = (const float4*)(attn + hd * 12);
        float4 a0 = ap[0], a1 = ap[1], a2 = ap[2];
        att[0]=a0.x; att[1]=a0.y; att[2]=a0.z; att[3]=a0.w;
        att[4]=a1.x; att[5]=a1.y; att[6]=a1.z; att[7]=a1.w;
        att[8]=a2.x; att[9]=a2.y; att[10]=a2.z; att[11]=a2.w;
        const float4* dp = (const float4*)(fd + (size_t)n * 96 + hd * 12);
        float4 d0 = dp[0], d1 = dp[1], d2 = dp[2];
        fdv[0]=d0.x; fdv[1]=d0.y; fdv[2]=d0.z; fdv[3]=d0.w;
        fdv[4]=d1.x; fdv[5]=d1.y; fdv[6]=d1.z; fdv[7]=d1.w;
        fdv[8]=d2.x; fdv[9]=d2.y; fdv[10]=d2.z; fdv[11]=d2.w;
    }
    int beg = row_start[n], end = row_start[n + 1];
    float m = -3.0e38f, den = 0.f;
    float acc[12];
#pragma unroll
    for (int d = 0; d < 12; ++d) acc[d] = 0.f;

    auto process = [&](const float4& s0, const float4& s1, const float4& s2) {
        float fsv[12];
        fsv[0]=s0.x; fsv[1]=s0.y; fsv[2]=s0.z; fsv[3]=s0.w;
        fsv[4]=s1.x; fsv[5]=s1.y; fsv[6]=s1.z; fsv[7]=s1.w;
        fsv[8]=s2.x; fsv[9]=s2.y; fsv[10]=s2.z; fsv[11]=s2.w;
        float logit = 0.f;
#pragma unroll
        for (int d = 0; d < 12; ++d) {
            float u = fsv[d] + fdv[d];
            u = u > 0.f ? u : 0.2f * u;
            logit = fmaf(u, att[d], logit);
        }
        float nm = fmaxf(m, logit);
        float cc = __expf(m - nm);
        float w  = __expf(logit - nm);
        den = fmaf(den, cc, w);
#pragma unroll
        for (int d = 0; d < 12; ++d) acc[d] = fmaf(acc[d], cc, w * fsv[d]);
        m = nm;
    };

    int e = beg;
    for (; e + 4 <= end; e += 4) {
        int i0 = csr_src[e], i1 = csr_src[e + 1], i2 = csr_src[e + 2], i3 = csr_src[e + 3];
        const float4* p0 = (const float4*)(fs + (size_t)i0 * 96 + hd * 12);
        const float4* p1 = (const float4*)(fs + (size_t)i1 * 96 + hd * 12);
        const float4* p2 = (const float4*)(fs + (size_t)i2 * 96 + hd * 12);
        const float4* p3 = (const float4*)(fs + (size_t)i3 * 96 + hd * 12);
        float4 a0 = p0[0], a1 = p0[1], a2 = p0[2];
        float4 b0 = p1[0], b1 = p1[1], b2 = p1[2];
        float4 c0 = p2[0], c1 = p2[1], c2 = p2[2];
        float4 d0 = p3[0], d1 = p3[1], d2 = p3[2];
        process(a0, a1, a2);
        process(b0, b1, b2);
        process(c0, c1, c2);
        process(d0, d1, d2);
    }
    for (; e < end; ++e) {
        int i0 = csr_src[e];
        const float4* p0 = (const float4*)(fs + (size_t)i0 * 96 + hd * 12);
        float4 a0 = p0[0], a1 = p0[1], a2 = p0[2];
        process(a0, a1, a2);
    }
    float inv = den > 0.f ? 1.f / den : 0.f;
    float* op = hout + (size_t)n * 96 + hd * 12;
#pragma unroll
    for (int d = 0; d < 12; ++d) op[d] = fmaxf(acc[d] * inv, 0.f);
}

// ---------------- per-graph max readout: stage 1, per-block LDS max -> partials ----------------
__global__ __launch_bounds__(384) void readout_partial(const float* __restrict__ h,
                                                       const int* __restrict__ graph_id,
                                                       float* __restrict__ partial, int N) {
    __shared__ int lhg[GG * 96];
    int t = threadIdx.x;
    for (int i = t; i < GG * 96; i += 384) lhg[i] = 0;
    __syncthreads();
    int f = t % 96, nl = t / 96;   // 4 nodes per iteration
    for (int n0 = blockIdx.x * 4; n0 < N; n0 += RB * 4) {
        int n = n0 + nl;
        if (n < N) {
            int g = graph_id[n];
            float v = h[(size_t)n * 96 + f];
            atomicMax(&lhg[g * 96 + f], __float_as_int(v));   // values >= 0
        }
    }
    __syncthreads();
    for (int i = t; i < GG * 96; i += 384)
        partial[(size_t)blockIdx.x * (GG * 96) + i] = __int_as_float(lhg[i]);
}

// ---------------- readout stage 2: reduce partials ----------------
__global__ void readout_reduce(const float* __restrict__ partial, float* __restrict__ hg) {
    int i = blockIdx.x * 256 + threadIdx.x;
    if (i < GG * 96) {
        float m = 0.f;
        for (int b = 0; b < RB; ++b) m = fmaxf(m, partial[(size_t)b * (GG * 96) + i]);
        hg[i] = m;
    }
}

// ---------------- classifier MLP: one block per graph ----------------
__global__ __launch_bounds__(96) void mlp_kernel(const float* __restrict__ hg,
                                                 const float* __restrict__ Wc1, const float* __restrict__ bc1,
                                                 const float* __restrict__ Wc2, const float* __restrict__ bc2,
                                                 const float* __restrict__ Wc3, const float* __restrict__ bc3,
                                                 float* __restrict__ out) {
    int g = blockIdx.x;
    int t = threadIdx.x;
    __shared__ float z0[96], z1[96], z2[48];
    z0[t] = hg[(size_t)g * 96 + t];
    __syncthreads();
    float s = bc1[t];
    for (int k = 0; k < 96; ++k) s = fmaf(z0[k], Wc1[k * 96 + t], s);
    z1[t] = fmaxf(s, 0.f);
    __syncthreads();
    if (t < 48) {
        float s2 = bc2[t];
        for (int k = 0; k < 96; ++k) s2 = fmaf(z1[k], Wc2[k * 48 + t], s2);
        z2[t] = fmaxf(s2, 0.f);
    }
    __syncthreads();
    if (t < 10) {
        float s3 = bc3[t];
        for (int k = 0; k < 48; ++k) s3 = fmaf(z2[k], Wc3[k * 10 + t], s3);
        out[(size_t)g * 10 + t] = s3;
    }
}

extern "C" void kernel_launch(void* const* d_in, const int* in_sizes, int n_in,
                              void* d_out, int out_size, void* d_ws, size_t ws_size,
                              hipStream_t stream) {
    const float* x        = (const float*)d_in[0];
    const int*   src      = (const int*)d_in[1];
    const int*   dst      = (const int*)d_in[2];
    const int*   graph_id = (const int*)d_in[3];
    const float* W1  = (const float*)d_in[4];
    const float* b1  = (const float*)d_in[5];
    const float* W2  = (const float*)d_in[6];
    const float* b2  = (const float*)d_in[7];
    const float* Ws  = (const float*)d_in[8];
    const float* bs  = (const float*)d_in[9];
    const float* Wd  = (const float*)d_in[10];
    const float* bd  = (const float*)d_in[11];
    const float* attn = (const float*)d_in[12];
    const float* Wc1 = (const float*)d_in[13];
    const float* bc1 = (const float*)d_in[14];
    const float* Wc2 = (const float*)d_in[15];
    const float* bc2 = (const float*)d_in[16];
    const float* Wc3 = (const float*)d_in[17];
    const float* bc3 = (const float*)d_in[18];
    float* out = (float*)d_out;

    char* ws = (char*)d_ws;
    size_t off = 0;
    auto alloc = [&](size_t bytes) {
        char* p = ws + off;
        off = (off + bytes + 255) & ~(size_t)255;
        return p;
    };
    int*   cnt_in    = (int*)alloc(Nn * 4);
    int*   cnt_out   = (int*)alloc(Nn * 4);
    int*   row_start = (int*)alloc((Nn + 1) * 4);
    int*   edge_slot = (int*)alloc(Ee * 4);
    int*   csr_src   = (int*)alloc(Ee * 4);
    float* degI_is   = (float*)alloc(Nn * 4);
    float* degO_is   = (float*)alloc(Nn * 4);
    float* bufH      = (float*)alloc((size_t)Nn * 96 * 4);
    float* bufT      = (float*)alloc((size_t)Nn * 96 * 4);
    float* bufFd     = (float*)alloc((size_t)Nn * 96 * 4);
    float* hg        = (float*)alloc(GG * 96 * 4);
    float* partial   = (float*)alloc((size_t)RB * GG * 96 * 4);
    int*   blk_sum   = (int*)alloc(128 * 4);
    int*   blk_off   = (int*)alloc(128 * 4);

    hipMemsetAsync(cnt_in, 0, Nn * 4, stream);
    hipMemsetAsync(cnt_out, 0, Nn * 4, stream);

    int eb = (Ee + 255) / 256;
    hist_kernel<<<eb, 256, 0, stream>>>(src, dst, cnt_out, cnt_in, edge_slot, Ee);
    scan1_kernel<<<SCAN_BLOCKS, 256, 0, stream>>>(cnt_in, row_start, blk_sum, Nn);
    scan2_kernel<<<1, 128, 0, stream>>>(blk_sum, blk_off, row_start, Nn);
    scan3_kernel<<<SCAN_BLOCKS, 256, 0, stream>>>(row_start, blk_off, Nn);
    node_setup<<<(Nn + 255) / 256, 256, 0, stream>>>(cnt_in, cnt_out, degI_is, degO_is, Nn);
    fill_kernel<<<eb, 256, 0, stream>>>(src, dst, row_start, edge_slot, csr_src, Ee);

    int gemm_blocks = (Nn + 63) / 64;
    int agg_blocks  = (Nn * 24 + 191) / 192;
    int gat_blocks  = (Nn * 8 + 255) / 256;

    // GraphConv 1: x[N,128] -> bufH
    gemm96<<<gemm_blocks, 192, 0, stream>>>(x, 128, W1, nullptr, degO_is, bufT, Nn);
    gc_agg<<<agg_blocks, 192, 0, stream>>>(bufT, row_start, csr_src, degI_is, b1, bufH, Nn);
    // GraphConv 2
    gemm96<<<gemm_blocks, 192, 0, stream>>>(bufH, 96, W2, nullptr, degO_is, bufT, Nn);
    gc_agg<<<agg_blocks, 192, 0, stream>>>(bufT, row_start, csr_src, degI_is, b2, bufH, Nn);

    // 3x GATv2: fused dual GEMM (fs,fd) then fused attention+aggregate
    for (int l = 0; l < 3; ++l) {
        const float* Wsl = Ws + (size_t)l * 96 * 96;
        const float* bsl = bs + (size_t)l * 96;
        const float* Wdl = Wd + (size_t)l * 96 * 96;
        const float* bdl = bd + (size_t)l * 96;
        const float* atl = attn + (size_t)l * 96;
        gemm96x2<<<gemm_blocks, 192, 0, stream>>>(bufH, Wsl, bsl, Wdl, bdl, bufT, bufFd, Nn);
        gat_agg<<<gat_blocks, 256, 0, stream>>>(bufT, bufFd, atl, row_start, csr_src, bufH, Nn);
    }

    readout_partial<<<RB, 384, 0, stream>>>(bufH, graph_id, partial, Nn);
    readout_reduce<<<(GG * 96 + 255) / 256, 256, 0, stream>>>(partial, hg);
    mlp_kernel<<<GG, 96, 0, stream>>>(hg, Wc1, bc1, Wc2, bc2, Wc3, bc3, out);
}